// Round 14
// baseline (335.294 us; speedup 1.0000x reference)
//
#include <hip/hip_runtime.h>

typedef unsigned short u16;
typedef unsigned long long u64;
using short8 = __attribute__((ext_vector_type(8))) short;
using f32x4  = __attribute__((ext_vector_type(4))) float;
using h16x4  = __attribute__((ext_vector_type(4))) _Float16;

constexpr int N_  = 65536;
constexpr int C_  = 256;
constexpr int K_  = 128;
constexpr int G_  = 32;
constexpr int NG_ = 2048;
constexpr int E_  = 2097152;
constexpr int NBIN_ = 2048;          // bins of 32 rows (row>>5)
constexpr int CAPB_ = 1280;          // per-bin capacity; Poisson(1024) + 8 sigma
constexpr int NCHK_ = 256;           // sort chunks (8192 edges each)

__device__ __forceinline__ u16 f2bf(float f) {
  unsigned u = __float_as_uint(f);
  unsigned r = u + 0x7FFF + ((u >> 16) & 1);
  return (u16)(r >> 16);
}
__device__ __forceinline__ float bf2f(u16 h) { return __uint_as_float((unsigned)h << 16); }
__device__ __forceinline__ u16 f2h(float f) {
  _Float16 h = (_Float16)f;
  u16 b; __builtin_memcpy(&b, &h, 2);
  return b;
}

__device__ __forceinline__ void gload_lds16(const void* g, void* l) {
  __builtin_amdgcn_global_load_lds((const __attribute__((address_space(1))) void*)g,
                                   (__attribute__((address_space(3))) void*)l, 16, 0, 0);
}

// ================= shared MFMA GEMM body (BT form): D[i,j] = sum_k A[i,k]*B[j,k] =================
constexpr int EPI_BF16  = 0;
constexpr int EPI_DECAY = 3;
constexpr int EPI_TRANS = 4;

template <int BM, int BN, int EPI>
__device__ __forceinline__ void gemm_body(
    char* smem, int bx, int by, int z,
    const u16* __restrict__ A, long sAz, int lda,
    const u16* __restrict__ B, long sBz, int ldb,
    int Kd,
    void* __restrict__ outp, long sCz, int ldc,
    const float* __restrict__ tpar, const float* __restrict__ evptr) {
  constexpr int WM = BM / 2, WN = BN / 2;
  constexpr int FM = WM / 16, FN = WN / 16;
  u16* Asm = (u16*)smem;
  u16* Bsm = Asm + BM * 32;
  const u16* Ab = A + (long)z * sAz + (long)bx * BM * lda;
  const u16* Bb = B + (long)z * sBz + (long)by * BN * ldb;
  int tid = threadIdx.x;
  int wave = tid >> 6, lane = tid & 63;
  int wm = wave >> 1, wn = wave & 1;

  f32x4 acc[FM][FN];
  #pragma unroll
  for (int m = 0; m < FM; ++m)
    #pragma unroll
    for (int n = 0; n < FN; ++n) acc[m][n] = {0.f, 0.f, 0.f, 0.f};

  const u16* aA = Ab + (size_t)(wave * 16 + (lane >> 2)) * lda + (lane & 3) * 8;
  const u16* aB = Bb + (size_t)(wave * 16 + (lane >> 2)) * ldb + (lane & 3) * 8;
  u16* lA = Asm + wave * 512;
  u16* lB = Bsm + wave * 512;
  int arow = wm * WM + (lane & 15);
  int brow = wn * WN + (lane & 15);
  int kof = (lane >> 4) * 8;

  for (int k0 = 0; k0 < Kd; k0 += 32) {
    #pragma unroll
    for (int j = 0; j < BM / 64; ++j) gload_lds16(aA + (size_t)j * 64 * lda + k0, lA + j * 2048);
    #pragma unroll
    for (int j = 0; j < BN / 64; ++j) gload_lds16(aB + (size_t)j * 64 * ldb + k0, lB + j * 2048);
    __syncthreads();
    short8 af[FM], bfr[FN];
    #pragma unroll
    for (int m = 0; m < FM; ++m) af[m] = *(const short8*)(Asm + (arow + m * 16) * 32 + kof);
    #pragma unroll
    for (int n = 0; n < FN; ++n) bfr[n] = *(const short8*)(Bsm + (brow + n * 16) * 32 + kof);
    #pragma unroll
    for (int m = 0; m < FM; ++m)
      #pragma unroll
      for (int n = 0; n < FN; ++n)
        acc[m][n] = __builtin_amdgcn_mfma_f32_16x16x32_bf16(af[m], bfr[n], acc[m][n], 0, 0, 0);
    __syncthreads();
  }

  #pragma unroll
  for (int m = 0; m < FM; ++m) {
    #pragma unroll
    for (int n = 0; n < FN; ++n) {
      int cc = by * BN + wn * WN + n * 16 + (lane & 15);
      int rb = bx * BM + wm * WM + m * 16 + ((lane >> 4) << 2);
      if constexpr (EPI == EPI_TRANS) {
        ushort4 o = {f2bf(acc[m][n][0]), f2bf(acc[m][n][1]), f2bf(acc[m][n][2]), f2bf(acc[m][n][3])};
        *(ushort4*)((u16*)outp + (long)z * sCz + (long)cc * ldc + rb) = o;
      } else if constexpr (EPI == EPI_DECAY) {
        float tv = fabsf(tpar[cc]);
        #pragma unroll
        for (int r = 0; r < 4; ++r) {
          float ee = fmaxf(evptr[(size_t)z * K_ + rb + r], 0.f);
          ((u16*)outp)[(long)z * sCz + (long)(rb + r) * ldc + cc] = f2bf(acc[m][n][r] * __expf(-tv * ee));
        }
      } else {
        #pragma unroll
        for (int r = 0; r < 4; ++r)
          ((u16*)outp)[(long)z * sCz + (long)(rb + r) * ldc + cc] = f2bf(acc[m][n][r]);
      }
    }
  }
}

template <int BM, int BN, int EPI>
__global__ __launch_bounds__(256) void k_gemm(
    const u16* __restrict__ A, long sAz, int lda,
    const u16* __restrict__ B, long sBz, int ldb,
    int Kd,
    void* __restrict__ outp, long sCz, int ldc,
    const float* __restrict__ tpar, const float* __restrict__ evptr) {
  __shared__ __align__(16) char smem[(BM + BN) * 32 * 2];
  gemm_body<BM, BN, EPI>(smem, blockIdx.x, blockIdx.y, blockIdx.z,
                         A, sAz, lda, B, sBz, ldb, Kd, outp, sCz, ldc, tpar, evptr);
}

// ================= phase A: hist(256) | conv_x | conv_E | f2bf W1,W2 | t256 gW | bc =================
constexpr int PA_HIST = NCHK_;
constexpr int PA_CVX  = 4096;
constexpr int PA_CVE  = 2048;
constexpr int PA_W1   = 512;
constexpr int PA_W2   = 256;
constexpr int PA_T256 = 16;
constexpr int PA_BC   = 16;
constexpr int PA_TOTAL = PA_HIST + PA_CVX + PA_CVE + PA_W1 + PA_W2 + PA_T256 + PA_BC;

__global__ __launch_bounds__(256) void k_phaseA(
    const int* __restrict__ row, int* __restrict__ bh,
    const float* __restrict__ x, const float* __restrict__ mass,
    u16* __restrict__ xhf, u16* __restrict__ xmT,
    const float* __restrict__ evecs, u16* __restrict__ Ebf, u16* __restrict__ EbfT,
    const float* __restrict__ W1, u16* __restrict__ W1bf,
    const float* __restrict__ W2, u16* __restrict__ W2bf,
    const float* __restrict__ gW, u16* __restrict__ gWT,
    const float* __restrict__ gb, const float* __restrict__ b1, float* __restrict__ bc) {
  __shared__ __align__(16) char smem[64 * 65 * 4 + 256];
  float (*tile)[65] = (float(*)[65])smem;
  float* msm = (float*)(smem + 64 * 65 * 4);
  int id = blockIdx.x, tid = threadIdx.x;

  if (id < PA_HIST) {                       // ---- LDS hist, no global atomics ----
    int* hist = (int*)smem;                 // [2048]
    #pragma unroll
    for (int j = 0; j < 8; ++j) hist[tid + j * 256] = 0;
    __syncthreads();
    int e0 = id * 8192 + tid;
    #pragma unroll 4
    for (int i = 0; i < 32; ++i)
      atomicAdd(&hist[row[e0 + i * 256] >> 5], 1);
    __syncthreads();
    #pragma unroll
    for (int j = 0; j < 8; ++j) {
      int bin = tid + j * 256;
      bh[(size_t)bin * NCHK_ + id] = hist[bin];
    }
    return;
  }
  id -= PA_HIST;
  if (id < PA_CVX) {                        // ---- conv_x: xhf(f16) + xmT(bf16, *mass, transposed) ----
    int r0 = (id >> 2) * 64, c0 = (id & 3) * 64;
    int tr = tid >> 4, tc4 = (tid & 15) * 4;
    #pragma unroll
    for (int p = 0; p < 4; ++p) {
      int r = p * 16 + tr;
      float4 v = *(const float4*)&x[(size_t)(r0 + r) * C_ + c0 + tc4];
      tile[r][tc4 + 0] = v.x; tile[r][tc4 + 1] = v.y; tile[r][tc4 + 2] = v.z; tile[r][tc4 + 3] = v.w;
      ushort4 o = {f2h(v.x), f2h(v.y), f2h(v.z), f2h(v.w)};
      *(ushort4*)&xhf[(size_t)(r0 + r) * C_ + c0 + tc4] = o;
    }
    if (tid < 64) msm[tid] = mass[r0 + tid];
    __syncthreads();
    int g = r0 >> 11, n0 = r0 & (NG_ - 1);
    #pragma unroll
    for (int p = 0; p < 4; ++p) {
      int cl = p * 16 + tr;
      ushort4 o;
      o.x = f2bf(tile[tc4 + 0][cl] * msm[tc4 + 0]);
      o.y = f2bf(tile[tc4 + 1][cl] * msm[tc4 + 1]);
      o.z = f2bf(tile[tc4 + 2][cl] * msm[tc4 + 2]);
      o.w = f2bf(tile[tc4 + 3][cl] * msm[tc4 + 3]);
      *(ushort4*)&xmT[((size_t)g * C_ + c0 + cl) * NG_ + n0 + tc4] = o;
    }
    return;
  }
  id -= PA_CVX;
  if (id < PA_CVE) {                        // ---- conv_E ----
    int r0 = (id >> 1) * 64, c0 = (id & 1) * 64;
    int tr = tid >> 4, tc4 = (tid & 15) * 4;
    #pragma unroll
    for (int p = 0; p < 4; ++p) {
      int r = p * 16 + tr;
      float4 v = *(const float4*)&evecs[(size_t)(r0 + r) * K_ + c0 + tc4];
      tile[r][tc4 + 0] = v.x; tile[r][tc4 + 1] = v.y; tile[r][tc4 + 2] = v.z; tile[r][tc4 + 3] = v.w;
      ushort4 o = {f2bf(v.x), f2bf(v.y), f2bf(v.z), f2bf(v.w)};
      *(ushort4*)&Ebf[(size_t)(r0 + r) * K_ + c0 + tc4] = o;
    }
    __syncthreads();
    int g = r0 >> 11, n0 = r0 & (NG_ - 1);
    #pragma unroll
    for (int p = 0; p < 4; ++p) {
      int cl = p * 16 + tr;
      ushort4 o = {f2bf(tile[tc4 + 0][cl]), f2bf(tile[tc4 + 1][cl]),
                   f2bf(tile[tc4 + 2][cl]), f2bf(tile[tc4 + 3][cl])};
      *(ushort4*)&EbfT[((size_t)g * K_ + c0 + cl) * NG_ + n0 + tc4] = o;
    }
    return;
  }
  id -= PA_CVE;
  if (id < PA_W1) { int i = id * 256 + tid; W1bf[i] = f2bf(W1[i]); return; }
  id -= PA_W1;
  if (id < PA_W2) { int i = id * 256 + tid; W2bf[i] = f2bf(W2[i]); return; }
  id -= PA_W2;
  if (id < PA_T256) {                       // ---- gW -> gWT ----
    int r0 = (id & 3) * 64, c0 = (id >> 2) * 64;
    int tr = tid >> 4, tc4 = (tid & 15) * 4;
    #pragma unroll
    for (int p = 0; p < 4; ++p) {
      int r = p * 16 + tr;
      float4 v = *(const float4*)&gW[(size_t)(r0 + r) * 256 + c0 + tc4];
      tile[r][tc4 + 0] = v.x; tile[r][tc4 + 1] = v.y; tile[r][tc4 + 2] = v.z; tile[r][tc4 + 3] = v.w;
    }
    __syncthreads();
    #pragma unroll
    for (int p = 0; p < 4; ++p) {
      int cl = p * 16 + tr;
      ushort4 o = {f2bf(tile[tc4 + 0][cl]), f2bf(tile[tc4 + 1][cl]),
                   f2bf(tile[tc4 + 2][cl]), f2bf(tile[tc4 + 3][cl])};
      *(ushort4*)&gWT[(size_t)(c0 + cl) * 256 + r0 + tc4] = o;
    }
    return;
  }
  id -= PA_T256;
  // ---- bc (parallel matvec) ----
  {
    float* red = (float*)smem;
    int cl = tid >> 4, js = tid & 15;
    int c = id * 16 + cl;
    const float* wrow = &W1[(size_t)c * 512 + 256 + js * 16];
    float s = 0.f;
    #pragma unroll
    for (int jj = 0; jj < 16; ++jj) s += wrow[jj] * gb[js * 16 + jj];
    red[cl * 17 + js] = s;
    __syncthreads();
    if (js == 0) {
      float tot = b1[c];
      #pragma unroll
      for (int q = 0; q < 16; ++q) tot += red[cl * 17 + q];
      bc[c] = tot;
    }
  }
}

// ================= scan: per-bin exclusive prefix over 256 chunks =================
__global__ __launch_bounds__(256) void k_scanOS(const int* __restrict__ bh, int* __restrict__ baseL,
                                                int* __restrict__ gcnt) {
  __shared__ int sc[256];
  int bin = blockIdx.x, tid = threadIdx.x;
  int v = bh[(size_t)bin * NCHK_ + tid];
  sc[tid] = v;
  __syncthreads();
  for (int o = 1; o < 256; o <<= 1) {
    int t = (tid >= o) ? sc[tid - o] : 0;
    __syncthreads();
    sc[tid] += t;
    __syncthreads();
  }
  baseL[(size_t)tid * NBIN_ + bin] = sc[tid] - v;
  if (tid == 255) gcnt[bin] = sc[255];
}

// ================= phase B: scatter(256) | Wc(4) | spec1(128), merged =================
constexpr int PB_SCAT = NCHK_;
constexpr int PB_WC   = 4;
constexpr int PB_SP1  = 128;
constexpr int PB_TOTAL = PB_SCAT + PB_WC + PB_SP1;

__global__ __launch_bounds__(256) void k_phaseB(
    const int* __restrict__ row, const int* __restrict__ col, const float* __restrict__ vals,
    const int* __restrict__ baseL, u64* __restrict__ epB,
    const u16* __restrict__ W1bf, const u16* __restrict__ gWT, u16* __restrict__ Wc,
    const u16* __restrict__ EbfT, const u16* __restrict__ xmT, u16* __restrict__ S,
    const float* __restrict__ tpar, const float* __restrict__ evptr) {
  __shared__ __align__(16) char smem[16384];
  int id = blockIdx.x, tid = threadIdx.x;

  if (id < PB_SCAT) {                       // ---- scatter: LDS rank, zero global atomics ----
    int* sbase = (int*)smem;                // [2048]
    int* cur   = sbase + NBIN_;             // [2048]
    #pragma unroll
    for (int j = 0; j < 8; ++j) {
      int b = tid + j * 256;
      sbase[b] = baseL[(size_t)id * NBIN_ + b];
      cur[b] = 0;
    }
    __syncthreads();
    int e0 = id * 8192 + tid;
    #pragma unroll 4
    for (int i = 0; i < 32; ++i) {
      int e = e0 + i * 256;
      int rr = row[e];
      int b = rr >> 5;
      int rk = atomicAdd(&cur[b], 1);       // LDS atomic
      int lpos = sbase[b] + rk;
      if (lpos < CAPB_)
        epB[(size_t)b * CAPB_ + lpos] =
            ((u64)(rr & 31) << 32) | ((u64)f2h(vals[e]) << 16) | (u64)(unsigned)col[e];
    }
    return;
  }
  id -= PB_SCAT;
  if (id < PB_WC) {                         // ---- Wc = W1b @ gW ----
    gemm_body<128, 128, EPI_BF16>(smem, id & 1, id >> 1, 0,
                                  W1bf + 256, 0, 512, gWT, 0, 256, 256,
                                  Wc, 0, 256, nullptr, nullptr);
    return;
  }
  id -= PB_WC;
  {                                         // ---- spec1: S[g,k,c] (decayed) ----
    int zz = id >> 2, rem = id & 3;
    gemm_body<64, 128, EPI_DECAY>(smem, rem & 1, rem >> 1, zz,
                                  EbfT, (long)K_ * NG_, NG_, xmT, (long)C_ * NG_, NG_, NG_,
                                  S, (long)K_ * C_, C_, tpar, evptr);
  }
}

// ================= gather: quad-cell interleaved MAC (16 loads in flight), 8-tile barrier sweep =================
__global__ __launch_bounds__(256) void k_gatherH(const u16* __restrict__ xhf, const int* __restrict__ gcnt,
                                                 const u64* __restrict__ epB, u16* __restrict__ gf) {
  __shared__ unsigned eL[CAPB_];
  __shared__ int chist[256];
  __shared__ int roff[257];
  __shared__ int sc[256];
  int b = blockIdx.x, tid = threadIdx.x;
  int wave = tid >> 6, lane = tid & 63;
  int n = gcnt[b]; if (n > CAPB_) n = CAPB_;
  chist[tid] = 0;
  __syncthreads();
  const u64* ebase = epB + (size_t)b * CAPB_;
  unsigned pkr[5]; int cellr[5]; int rkr[5];
  #pragma unroll
  for (int q = 0; q < 5; ++q) {
    int i = tid + q * 256;
    bool ok = i < n;
    u64 pk = ok ? ebase[i] : 0;
    int cell = (int)((pk & 0xFFFFu) >> 13) * 32 + ((int)(pk >> 32) & 31);
    pkr[q] = (unsigned)pk; cellr[q] = cell; rkr[q] = 0;
    if (ok) rkr[q] = atomicAdd(&chist[cell], 1);
  }
  __syncthreads();
  int s = chist[tid];
  sc[tid] = s;
  __syncthreads();
  for (int o = 1; o < 256; o <<= 1) {
    int v = (tid >= o) ? sc[tid - o] : 0;
    __syncthreads();
    sc[tid] += v;
    __syncthreads();
  }
  roff[tid] = sc[tid] - s;
  if (tid == 255) roff[256] = sc[255];
  __syncthreads();
  #pragma unroll
  for (int q = 0; q < 5; ++q) {
    int i = tid + q * 256;
    if (i < n) eL[roff[cellr[q]] + rkr[q]] = pkr[q];
  }
  __syncthreads();

  const u16* xb = xhf + lane * 4;
  f32x4 acc[8];
  #pragma unroll
  for (int k = 0; k < 8; ++k) acc[k] = {0.f, 0.f, 0.f, 0.f};
  for (int t = 0; t < 8; ++t) {
    #pragma unroll
    for (int k4 = 0; k4 < 8; k4 += 4) {
      int c0 = t * 32 + wave * 8 + k4;
      int j0 = roff[c0 + 0], e0 = roff[c0 + 1];
      int j1 = roff[c0 + 1], e1 = roff[c0 + 2];
      int j2 = roff[c0 + 2], e2 = roff[c0 + 3];
      int j3 = roff[c0 + 3], e3 = roff[c0 + 4];
      while (j0 < e0 || j1 < e1 || j2 < e2 || j3 < e3) {
        unsigned u[16]; h16x4 xv[16];
        #pragma unroll
        for (int q = 0; q < 4; ++q) {
          u[q]      = (j0 + q < e0) ? eL[j0 + q] : 0u;   // dummy: col 0, val +0
          u[4 + q]  = (j1 + q < e1) ? eL[j1 + q] : 0u;
          u[8 + q]  = (j2 + q < e2) ? eL[j2 + q] : 0u;
          u[12 + q] = (j3 + q < e3) ? eL[j3 + q] : 0u;
        }
        #pragma unroll
        for (int q = 0; q < 16; ++q)
          xv[q] = *(const h16x4*)(xb + (size_t)(u[q] & 0xFFFFu) * C_);
        #pragma unroll
        for (int i4 = 0; i4 < 4; ++i4) {
          #pragma unroll
          for (int q = 0; q < 4; ++q) {
            u16 hb = (u16)(u[i4 * 4 + q] >> 16);
            _Float16 hv; __builtin_memcpy(&hv, &hb, 2);
            float v = (float)hv;
            acc[k4 + i4][0] += (float)xv[i4 * 4 + q][0] * v;   // v_fma_mix_f32
            acc[k4 + i4][1] += (float)xv[i4 * 4 + q][1] * v;
            acc[k4 + i4][2] += (float)xv[i4 * 4 + q][2] * v;
            acc[k4 + i4][3] += (float)xv[i4 * 4 + q][3] * v;
          }
        }
        j0 += 4; j1 += 4; j2 += 4; j3 += 4;
      }
    }
    __syncthreads();   // tile-phase alignment (L2 locality window)
  }
  int r0 = b * 32 + wave * 8;
  #pragma unroll
  for (int k = 0; k < 8; ++k) {
    ushort4 o = {f2bf(acc[k][0]), f2bf(acc[k][1]), f2bf(acc[k][2]), f2bf(acc[k][3])};
    *(ushort4*)&gf[(size_t)(r0 + k) * C_ + lane * 4] = o;
  }
}

// ================= fused MLP: h in swizzled LDS; y = x + h@W2^T + b2; LN -> out =================
__global__ __launch_bounds__(256) void k_mlp(
    const u16* __restrict__ Eb, const u16* __restrict__ Tt,
    const u16* __restrict__ gf, const u16* __restrict__ Wc,
    const float* __restrict__ bc,
    const u16* __restrict__ W2bf, const float* __restrict__ b2,
    const float* __restrict__ x, const float* __restrict__ lng, const float* __restrict__ lnb,
    float* __restrict__ out) {
  __shared__ __align__(16) u16 Asm[64 * 32];
  __shared__ __align__(16) u16 Bsm[256 * 32];
  __shared__ __align__(16) u16 hs[64 * 256];
  __shared__ float ps1[64][4], ps2[64][4];
  int i0 = blockIdx.x * 64;
  int g = i0 >> 11;
  int tid = threadIdx.x, wave = tid >> 6, lane = tid & 63;
  int wn = wave;
  int srow = wave * 16 + (lane >> 2), scol = (lane & 3) * 8;
  u16* lA = Asm + wave * 512;
  u16* lB = Bsm + wave * 512;
  int arow = lane & 15;
  int brow = wn * 64 + (lane & 15);
  int kof = (lane >> 4) * 8;

  f32x4 acc[4][4];
  #pragma unroll
  for (int m = 0; m < 4; ++m)
    #pragma unroll
    for (int n = 0; n < 4; ++n) acc[m][n] = {0.f, 0.f, 0.f, 0.f};

  {
    const u16* aA = Eb + (size_t)(i0 + srow) * K_ + scol;
    const u16* aB = Tt + (size_t)g * C_ * K_ + (size_t)srow * K_ + scol;
    for (int k0 = 0; k0 < 128; k0 += 32) {
      gload_lds16(aA + k0, lA);
      #pragma unroll
      for (int j = 0; j < 4; ++j) gload_lds16(aB + (size_t)j * 64 * K_ + k0, lB + j * 2048);
      __syncthreads();
      short8 af[4], bfr[4];
      #pragma unroll
      for (int m = 0; m < 4; ++m) af[m] = *(const short8*)(Asm + (arow + m * 16) * 32 + kof);
      #pragma unroll
      for (int n = 0; n < 4; ++n) bfr[n] = *(const short8*)(Bsm + (brow + n * 16) * 32 + kof);
      #pragma unroll
      for (int m = 0; m < 4; ++m)
        #pragma unroll
        for (int n = 0; n < 4; ++n)
          acc[m][n] = __builtin_amdgcn_mfma_f32_16x16x32_bf16(af[m], bfr[n], acc[m][n], 0, 0, 0);
      __syncthreads();
    }
  }
  {
    const u16* aA = gf + (size_t)(i0 + srow) * C_ + scol;
    const u16* aB = Wc + (size_t)srow * C_ + scol;
    for (int k0 = 0; k0 < 256; k0 += 32) {
      gload_lds16(aA + k0, lA);
      #pragma unroll
      for (int j = 0; j < 4; ++j) gload_lds16(aB + (size_t)j * 64 * C_ + k0, lB + j * 2048);
      __syncthreads();
      short8 af[4], bfr[4];
      #pragma unroll
      for (int m = 0; m < 4; ++m) af[m] = *(const short8*)(Asm + (arow + m * 16) * 32 + kof);
      #pragma unroll
      for (int n = 0; n < 4; ++n) bfr[n] = *(const short8*)(Bsm + (brow + n * 16) * 32 + kof);
      #pragma unroll
      for (int m = 0; m < 4; ++m)
        #pragma unroll
        for (int n = 0; n < 4; ++n)
          acc[m][n] = __builtin_amdgcn_mfma_f32_16x16x32_bf16(af[m], bfr[n], acc[m][n], 0, 0, 0);
      __syncthreads();
    }
  }
  #pragma unroll
  for (int n = 0; n < 4; ++n) {
    int cc = wn * 64 + n * 16 + (lane & 15);
    float bv = bc[cc];
    #pragma unroll
    for (int m = 0; m < 4; ++m) {
      #pragma unroll
      for (int r = 0; r < 4; ++r) {
        int rb = m * 16 + ((lane >> 4) << 2) + r;
        hs[(rb * 256 + cc) ^ ((rb & 7) << 3)] = f2bf(fmaxf(acc[m][n][r] + bv, 0.f));
      }
    }
  }
  __syncthreads();

  #pragma unroll
  for (int m = 0; m < 4; ++m)
    #pragma unroll
    for (int n = 0; n < 4; ++n) acc[m][n] = {0.f, 0.f, 0.f, 0.f};
  {
    const u16* aB = W2bf + (size_t)srow * C_ + scol;
    for (int k0 = 0; k0 < 256; k0 += 32) {
      #pragma unroll
      for (int j = 0; j < 4; ++j) gload_lds16(aB + (size_t)j * 64 * C_ + k0, lB + j * 2048);
      __syncthreads();
      short8 af[4], bfr[4];
      #pragma unroll
      for (int m = 0; m < 4; ++m) {
        int ar = arow + m * 16;
        af[m] = *(const short8*)(hs + ((ar * 256 + k0 + kof) ^ ((ar & 7) << 3)));
      }
      #pragma unroll
      for (int n = 0; n < 4; ++n) bfr[n] = *(const short8*)(Bsm + (brow + n * 16) * 32 + kof);
      #pragma unroll
      for (int m = 0; m < 4; ++m)
        #pragma unroll
        for (int n = 0; n < 4; ++n)
          acc[m][n] = __builtin_amdgcn_mfma_f32_16x16x32_bf16(af[m], bfr[n], acc[m][n], 0, 0, 0);
      __syncthreads();
    }
  }
  float bb[4], lg[4], lb[4];
  #pragma unroll
  for (int n = 0; n < 4; ++n) {
    int cc = wn * 64 + n * 16 + (lane & 15);
    bb[n] = b2[cc]; lg[n] = lng[cc]; lb[n] = lnb[cc];
  }
  #pragma unroll
  for (int m = 0; m < 4; ++m) {
    #pragma unroll
    for (int r = 0; r < 4; ++r) {
      int rl = m * 16 + ((lane >> 4) << 2) + r;
      #pragma unroll
      for (int n = 0; n < 4; ++n) {
        int cc = wn * 64 + n * 16 + (lane & 15);
        acc[m][n][r] += bb[n] + x[(size_t)(i0 + rl) * C_ + cc];
      }
    }
  }
  #pragma unroll
  for (int m = 0; m < 4; ++m) {
    #pragma unroll
    for (int r = 0; r < 4; ++r) {
      float t1 = acc[m][0][r] + acc[m][1][r] + acc[m][2][r] + acc[m][3][r];
      float t2 = acc[m][0][r] * acc[m][0][r] + acc[m][1][r] * acc[m][1][r] +
                 acc[m][2][r] * acc[m][2][r] + acc[m][3][r] * acc[m][3][r];
      #pragma unroll
      for (int msk = 1; msk < 16; msk <<= 1) {
        t1 += __shfl_xor(t1, msk);
        t2 += __shfl_xor(t2, msk);
      }
      if ((lane & 15) == 0) {
        int rl = m * 16 + ((lane >> 4) << 2) + r;
        ps1[rl][wn] = t1; ps2[rl][wn] = t2;
      }
    }
  }
  __syncthreads();
  #pragma unroll
  for (int m = 0; m < 4; ++m) {
    #pragma unroll
    for (int r = 0; r < 4; ++r) {
      int rl = m * 16 + ((lane >> 4) << 2) + r;
      float tot1 = ps1[rl][0] + ps1[rl][1] + ps1[rl][2] + ps1[rl][3];
      float tot2 = ps2[rl][0] + ps2[rl][1] + ps2[rl][2] + ps2[rl][3];
      float mu = tot1 * (1.f / 256.f);
      float var = fmaxf(tot2 * (1.f / 256.f) - mu * mu, 0.f);
      float rs = rsqrtf(var + 1e-5f);
      #pragma unroll
      for (int n = 0; n < 4; ++n) {
        int cc = wn * 64 + n * 16 + (lane & 15);
        out[(size_t)(i0 + rl) * C_ + cc] = (acc[m][n][r] - mu) * rs * lg[n] + lb[n];
      }
    }
  }
}

extern "C" void kernel_launch(void* const* d_in, const int* in_sizes, int n_in,
                              void* d_out, int out_size, void* d_ws, size_t ws_size,
                              hipStream_t stream) {
  const float* x        = (const float*)d_in[0];
  const float* ev       = (const float*)d_in[1];
  const float* evecs    = (const float*)d_in[2];
  const float* mass     = (const float*)d_in[3];
  const int*   row      = (const int*)d_in[4];
  const int*   col      = (const int*)d_in[5];
  const float* vals     = (const float*)d_in[6];
  const float* t_params = (const float*)d_in[7];
  const float* gW       = (const float*)d_in[8];
  const float* gb       = (const float*)d_in[9];
  const float* W1       = (const float*)d_in[10];
  const float* b1       = (const float*)d_in[11];
  const float* W2       = (const float*)d_in[12];
  const float* b2       = (const float*)d_in[13];
  const float* lng      = (const float*)d_in[14];
  const float* lnb      = (const float*)d_in[15];
  float* out = (float*)d_out;

  char* p = (char*)d_ws;
  u16* xhf  = (u16*)p; p += (size_t)N_ * C_ * 2;          // 32MB (f16 x-table for gather)
  u16* xmT  = (u16*)p; p += (size_t)G_ * C_ * NG_ * 2;    // 32MB (dead after spec1 -> reused as gf)
  u16* EbfT = (u16*)p; p += (size_t)G_ * K_ * NG_ * 2;    // 16MB
  u16* Ebf  = (u16*)p; p += (size_t)N_ * K_ * 2;          // 16MB
  u16* S    = (u16*)p; p += (size_t)G_ * K_ * C_ * 2;     // 2MB
  u16* Tt   = (u16*)p; p += (size_t)G_ * C_ * K_ * 2;     // 2MB
  u16* W1bf = (u16*)p; p += (size_t)C_ * 512 * 2;
  u16* W2bf = (u16*)p; p += (size_t)C_ * C_ * 2;
  u16* gWT  = (u16*)p; p += (size_t)C_ * C_ * 2;
  u16* Wc   = (u16*)p; p += (size_t)C_ * C_ * 2;
  float* bc = (float*)p; p += (size_t)C_ * 4;
  int* gcnt = (int*)p; p += (size_t)NBIN_ * 4;            // 8KB
  int* bh   = (int*)p; p += (size_t)NBIN_ * NCHK_ * 4;    // 2MB
  int* baseL= (int*)p; p += (size_t)NCHK_ * NBIN_ * 4;    // 2MB
  u64* epB  = (u64*)p; p += (size_t)NBIN_ * CAPB_ * 8;    // 21MB
  u16* gf   = xmT;     // overlay: gather runs after spec1 (phaseB) consumed xmT

  // phase A: LDS hist + all conversions + bc
  k_phaseA<<<PA_TOTAL, 256, 0, stream>>>(row, bh, x, mass, xhf, xmT,
                                         evecs, Ebf, EbfT, W1, W1bf, W2, W2bf,
                                         gW, gWT, gb, b1, bc);
  // per-bin chunk scan
  k_scanOS<<<NBIN_, 256, 0, stream>>>(bh, baseL, gcnt);
  // phase B: scatter + Wc + spec1 merged
  k_phaseB<<<PB_TOTAL, 256, 0, stream>>>(row, col, vals, baseL, epB,
                                         W1bf, gWT, Wc, EbfT, xmT, S, t_params, ev);
  // Tt[g][c][k] = (S' @ W1a^T)^T
  k_gemm<128, 128, EPI_TRANS><<<dim3(1, 2, G_), 256, 0, stream>>>(
      S, (long)K_ * C_, C_, W1bf, 0, 512, 256,
      Tt, (long)C_ * K_, K_, nullptr, nullptr);

  // gather (exclusive residency; xmT dead -> gf overlays it); quad-cell interleaved MAC
  k_gatherH<<<NBIN_, 256, 0, stream>>>(xhf, gcnt, epB, gf);

  // fused MLP + residual + LN
  k_mlp<<<N_ / 64, 256, 0, stream>>>(Ebf, Tt, gf, Wc, bc, W2bf, b2, x, lng, lnb, out);
}

// Round 15
// 321.790 us; speedup vs baseline: 1.0420x; 1.0420x over previous
//
#include <hip/hip_runtime.h>

typedef unsigned short u16;
typedef unsigned long long u64;
using short8 = __attribute__((ext_vector_type(8))) short;
using f32x4  = __attribute__((ext_vector_type(4))) float;
using h16x4  = __attribute__((ext_vector_type(4))) _Float16;

constexpr int N_  = 65536;
constexpr int C_  = 256;
constexpr int K_  = 128;
constexpr int G_  = 32;
constexpr int NG_ = 2048;
constexpr int E_  = 2097152;
constexpr int NBIN_ = 2048;          // bins of 32 rows (row>>5)
constexpr int CAPB_ = 1280;          // per-bin capacity; Poisson(1024) + 8 sigma
constexpr int NCHK_ = 256;           // sort chunks (8192 edges each)

__device__ __forceinline__ u16 f2bf(float f) {
  unsigned u = __float_as_uint(f);
  unsigned r = u + 0x7FFF + ((u >> 16) & 1);
  return (u16)(r >> 16);
}
__device__ __forceinline__ float bf2f(u16 h) { return __uint_as_float((unsigned)h << 16); }
__device__ __forceinline__ u16 f2h(float f) {
  _Float16 h = (_Float16)f;
  u16 b; __builtin_memcpy(&b, &h, 2);
  return b;
}

__device__ __forceinline__ void gload_lds16(const void* g, void* l) {
  __builtin_amdgcn_global_load_lds((const __attribute__((address_space(1))) void*)g,
                                   (__attribute__((address_space(3))) void*)l, 16, 0, 0);
}

// ================= shared MFMA GEMM body (BT form): D[i,j] = sum_k A[i,k]*B[j,k] =================
constexpr int EPI_BF16  = 0;
constexpr int EPI_DECAY = 3;
constexpr int EPI_TRANS = 4;

template <int BM, int BN, int EPI>
__device__ __forceinline__ void gemm_body(
    char* smem, int bx, int by, int z,
    const u16* __restrict__ A, long sAz, int lda,
    const u16* __restrict__ B, long sBz, int ldb,
    int Kd,
    void* __restrict__ outp, long sCz, int ldc,
    const float* __restrict__ tpar, const float* __restrict__ evptr) {
  constexpr int WM = BM / 2, WN = BN / 2;
  constexpr int FM = WM / 16, FN = WN / 16;
  u16* Asm = (u16*)smem;
  u16* Bsm = Asm + BM * 32;
  const u16* Ab = A + (long)z * sAz + (long)bx * BM * lda;
  const u16* Bb = B + (long)z * sBz + (long)by * BN * ldb;
  int tid = threadIdx.x;
  int wave = tid >> 6, lane = tid & 63;
  int wm = wave >> 1, wn = wave & 1;

  f32x4 acc[FM][FN];
  #pragma unroll
  for (int m = 0; m < FM; ++m)
    #pragma unroll
    for (int n = 0; n < FN; ++n) acc[m][n] = {0.f, 0.f, 0.f, 0.f};

  const u16* aA = Ab + (size_t)(wave * 16 + (lane >> 2)) * lda + (lane & 3) * 8;
  const u16* aB = Bb + (size_t)(wave * 16 + (lane >> 2)) * ldb + (lane & 3) * 8;
  u16* lA = Asm + wave * 512;
  u16* lB = Bsm + wave * 512;
  int arow = wm * WM + (lane & 15);
  int brow = wn * WN + (lane & 15);
  int kof = (lane >> 4) * 8;

  for (int k0 = 0; k0 < Kd; k0 += 32) {
    #pragma unroll
    for (int j = 0; j < BM / 64; ++j) gload_lds16(aA + (size_t)j * 64 * lda + k0, lA + j * 2048);
    #pragma unroll
    for (int j = 0; j < BN / 64; ++j) gload_lds16(aB + (size_t)j * 64 * ldb + k0, lB + j * 2048);
    __syncthreads();
    short8 af[FM], bfr[FN];
    #pragma unroll
    for (int m = 0; m < FM; ++m) af[m] = *(const short8*)(Asm + (arow + m * 16) * 32 + kof);
    #pragma unroll
    for (int n = 0; n < FN; ++n) bfr[n] = *(const short8*)(Bsm + (brow + n * 16) * 32 + kof);
    #pragma unroll
    for (int m = 0; m < FM; ++m)
      #pragma unroll
      for (int n = 0; n < FN; ++n)
        acc[m][n] = __builtin_amdgcn_mfma_f32_16x16x32_bf16(af[m], bfr[n], acc[m][n], 0, 0, 0);
    __syncthreads();
  }

  #pragma unroll
  for (int m = 0; m < FM; ++m) {
    #pragma unroll
    for (int n = 0; n < FN; ++n) {
      int cc = by * BN + wn * WN + n * 16 + (lane & 15);
      int rb = bx * BM + wm * WM + m * 16 + ((lane >> 4) << 2);
      if constexpr (EPI == EPI_TRANS) {
        ushort4 o = {f2bf(acc[m][n][0]), f2bf(acc[m][n][1]), f2bf(acc[m][n][2]), f2bf(acc[m][n][3])};
        *(ushort4*)((u16*)outp + (long)z * sCz + (long)cc * ldc + rb) = o;
      } else if constexpr (EPI == EPI_DECAY) {
        float tv = fabsf(tpar[cc]);
        #pragma unroll
        for (int r = 0; r < 4; ++r) {
          float ee = fmaxf(evptr[(size_t)z * K_ + rb + r], 0.f);
          ((u16*)outp)[(long)z * sCz + (long)(rb + r) * ldc + cc] = f2bf(acc[m][n][r] * __expf(-tv * ee));
        }
      } else {
        #pragma unroll
        for (int r = 0; r < 4; ++r)
          ((u16*)outp)[(long)z * sCz + (long)(rb + r) * ldc + cc] = f2bf(acc[m][n][r]);
      }
    }
  }
}

template <int BM, int BN, int EPI>
__global__ __launch_bounds__(256) void k_gemm(
    const u16* __restrict__ A, long sAz, int lda,
    const u16* __restrict__ B, long sBz, int ldb,
    int Kd,
    void* __restrict__ outp, long sCz, int ldc,
    const float* __restrict__ tpar, const float* __restrict__ evptr) {
  __shared__ __align__(16) char smem[(BM + BN) * 32 * 2];
  gemm_body<BM, BN, EPI>(smem, blockIdx.x, blockIdx.y, blockIdx.z,
                         A, sAz, lda, B, sBz, ldb, Kd, outp, sCz, ldc, tpar, evptr);
}

// ================= phase A: hist(256) | conv_x | conv_E | f2bf W1,W2 | t256 gW | bc =================
constexpr int PA_HIST = NCHK_;
constexpr int PA_CVX  = 4096;
constexpr int PA_CVE  = 2048;
constexpr int PA_W1   = 512;
constexpr int PA_W2   = 256;
constexpr int PA_T256 = 16;
constexpr int PA_BC   = 16;
constexpr int PA_TOTAL = PA_HIST + PA_CVX + PA_CVE + PA_W1 + PA_W2 + PA_T256 + PA_BC;

__global__ __launch_bounds__(256) void k_phaseA(
    const int* __restrict__ row, int* __restrict__ bh,
    const float* __restrict__ x, const float* __restrict__ mass,
    u16* __restrict__ xhf, u16* __restrict__ xmT,
    const float* __restrict__ evecs, u16* __restrict__ Ebf, u16* __restrict__ EbfT,
    const float* __restrict__ W1, u16* __restrict__ W1bf,
    const float* __restrict__ W2, u16* __restrict__ W2bf,
    const float* __restrict__ gW, u16* __restrict__ gWT,
    const float* __restrict__ gb, const float* __restrict__ b1, float* __restrict__ bc) {
  __shared__ __align__(16) char smem[64 * 65 * 4 + 256];
  float (*tile)[65] = (float(*)[65])smem;
  float* msm = (float*)(smem + 64 * 65 * 4);
  int id = blockIdx.x, tid = threadIdx.x;

  if (id < PA_HIST) {                       // ---- LDS hist, no global atomics ----
    int* hist = (int*)smem;                 // [2048]
    #pragma unroll
    for (int j = 0; j < 8; ++j) hist[tid + j * 256] = 0;
    __syncthreads();
    int e0 = id * 8192 + tid;
    #pragma unroll 4
    for (int i = 0; i < 32; ++i)
      atomicAdd(&hist[row[e0 + i * 256] >> 5], 1);
    __syncthreads();
    #pragma unroll
    for (int j = 0; j < 8; ++j) {
      int bin = tid + j * 256;
      bh[(size_t)bin * NCHK_ + id] = hist[bin];
    }
    return;
  }
  id -= PA_HIST;
  if (id < PA_CVX) {                        // ---- conv_x: xhf(f16) + xmT(bf16, *mass, transposed) ----
    int r0 = (id >> 2) * 64, c0 = (id & 3) * 64;
    int tr = tid >> 4, tc4 = (tid & 15) * 4;
    #pragma unroll
    for (int p = 0; p < 4; ++p) {
      int r = p * 16 + tr;
      float4 v = *(const float4*)&x[(size_t)(r0 + r) * C_ + c0 + tc4];
      tile[r][tc4 + 0] = v.x; tile[r][tc4 + 1] = v.y; tile[r][tc4 + 2] = v.z; tile[r][tc4 + 3] = v.w;
      ushort4 o = {f2h(v.x), f2h(v.y), f2h(v.z), f2h(v.w)};
      *(ushort4*)&xhf[(size_t)(r0 + r) * C_ + c0 + tc4] = o;
    }
    if (tid < 64) msm[tid] = mass[r0 + tid];
    __syncthreads();
    int g = r0 >> 11, n0 = r0 & (NG_ - 1);
    #pragma unroll
    for (int p = 0; p < 4; ++p) {
      int cl = p * 16 + tr;
      ushort4 o;
      o.x = f2bf(tile[tc4 + 0][cl] * msm[tc4 + 0]);
      o.y = f2bf(tile[tc4 + 1][cl] * msm[tc4 + 1]);
      o.z = f2bf(tile[tc4 + 2][cl] * msm[tc4 + 2]);
      o.w = f2bf(tile[tc4 + 3][cl] * msm[tc4 + 3]);
      *(ushort4*)&xmT[((size_t)g * C_ + c0 + cl) * NG_ + n0 + tc4] = o;
    }
    return;
  }
  id -= PA_CVX;
  if (id < PA_CVE) {                        // ---- conv_E ----
    int r0 = (id >> 1) * 64, c0 = (id & 1) * 64;
    int tr = tid >> 4, tc4 = (tid & 15) * 4;
    #pragma unroll
    for (int p = 0; p < 4; ++p) {
      int r = p * 16 + tr;
      float4 v = *(const float4*)&evecs[(size_t)(r0 + r) * K_ + c0 + tc4];
      tile[r][tc4 + 0] = v.x; tile[r][tc4 + 1] = v.y; tile[r][tc4 + 2] = v.z; tile[r][tc4 + 3] = v.w;
      ushort4 o = {f2bf(v.x), f2bf(v.y), f2bf(v.z), f2bf(v.w)};
      *(ushort4*)&Ebf[(size_t)(r0 + r) * K_ + c0 + tc4] = o;
    }
    __syncthreads();
    int g = r0 >> 11, n0 = r0 & (NG_ - 1);
    #pragma unroll
    for (int p = 0; p < 4; ++p) {
      int cl = p * 16 + tr;
      ushort4 o = {f2bf(tile[tc4 + 0][cl]), f2bf(tile[tc4 + 1][cl]),
                   f2bf(tile[tc4 + 2][cl]), f2bf(tile[tc4 + 3][cl])};
      *(ushort4*)&EbfT[((size_t)g * K_ + c0 + cl) * NG_ + n0 + tc4] = o;
    }
    return;
  }
  id -= PA_CVE;
  if (id < PA_W1) { int i = id * 256 + tid; W1bf[i] = f2bf(W1[i]); return; }
  id -= PA_W1;
  if (id < PA_W2) { int i = id * 256 + tid; W2bf[i] = f2bf(W2[i]); return; }
  id -= PA_W2;
  if (id < PA_T256) {                       // ---- gW -> gWT ----
    int r0 = (id & 3) * 64, c0 = (id >> 2) * 64;
    int tr = tid >> 4, tc4 = (tid & 15) * 4;
    #pragma unroll
    for (int p = 0; p < 4; ++p) {
      int r = p * 16 + tr;
      float4 v = *(const float4*)&gW[(size_t)(r0 + r) * 256 + c0 + tc4];
      tile[r][tc4 + 0] = v.x; tile[r][tc4 + 1] = v.y; tile[r][tc4 + 2] = v.z; tile[r][tc4 + 3] = v.w;
    }
    __syncthreads();
    #pragma unroll
    for (int p = 0; p < 4; ++p) {
      int cl = p * 16 + tr;
      ushort4 o = {f2bf(tile[tc4 + 0][cl]), f2bf(tile[tc4 + 1][cl]),
                   f2bf(tile[tc4 + 2][cl]), f2bf(tile[tc4 + 3][cl])};
      *(ushort4*)&gWT[(size_t)(c0 + cl) * 256 + r0 + tc4] = o;
    }
    return;
  }
  id -= PA_T256;
  // ---- bc (parallel matvec) ----
  {
    float* red = (float*)smem;
    int cl = tid >> 4, js = tid & 15;
    int c = id * 16 + cl;
    const float* wrow = &W1[(size_t)c * 512 + 256 + js * 16];
    float s = 0.f;
    #pragma unroll
    for (int jj = 0; jj < 16; ++jj) s += wrow[jj] * gb[js * 16 + jj];
    red[cl * 17 + js] = s;
    __syncthreads();
    if (js == 0) {
      float tot = b1[c];
      #pragma unroll
      for (int q = 0; q < 16; ++q) tot += red[cl * 17 + q];
      bc[c] = tot;
    }
  }
}

// ================= scan: per-bin exclusive prefix over 256 chunks =================
__global__ __launch_bounds__(256) void k_scanOS(const int* __restrict__ bh, int* __restrict__ baseL,
                                                int* __restrict__ gcnt) {
  __shared__ int sc[256];
  int bin = blockIdx.x, tid = threadIdx.x;
  int v = bh[(size_t)bin * NCHK_ + tid];
  sc[tid] = v;
  __syncthreads();
  for (int o = 1; o < 256; o <<= 1) {
    int t = (tid >= o) ? sc[tid - o] : 0;
    __syncthreads();
    sc[tid] += t;
    __syncthreads();
  }
  baseL[(size_t)tid * NBIN_ + bin] = sc[tid] - v;
  if (tid == 255) gcnt[bin] = sc[255];
}

// ================= phase B: scatter(256) | Wc(4) =================
constexpr int PB_SCAT = NCHK_;
constexpr int PB_WC   = 4;
constexpr int PB_TOTAL = PB_SCAT + PB_WC;

__global__ __launch_bounds__(256) void k_phaseB(
    const int* __restrict__ row, const int* __restrict__ col, const float* __restrict__ vals,
    const int* __restrict__ baseL, u64* __restrict__ epB,
    const u16* __restrict__ W1bf, const u16* __restrict__ gWT, u16* __restrict__ Wc) {
  __shared__ __align__(16) char smem[16384];
  int id = blockIdx.x, tid = threadIdx.x;

  if (id < PB_SCAT) {                       // ---- scatter: LDS rank, zero global atomics ----
    int* sbase = (int*)smem;                // [2048]
    int* cur   = sbase + NBIN_;             // [2048]
    #pragma unroll
    for (int j = 0; j < 8; ++j) {
      int b = tid + j * 256;
      sbase[b] = baseL[(size_t)id * NBIN_ + b];
      cur[b] = 0;
    }
    __syncthreads();
    int e0 = id * 8192 + tid;
    #pragma unroll 4
    for (int i = 0; i < 32; ++i) {
      int e = e0 + i * 256;
      int rr = row[e];
      int b = rr >> 5;
      int rk = atomicAdd(&cur[b], 1);       // LDS atomic
      int lpos = sbase[b] + rk;
      if (lpos < CAPB_)
        epB[(size_t)b * CAPB_ + lpos] =
            ((u64)(rr & 31) << 32) | ((u64)f2h(vals[e]) << 16) | (u64)(unsigned)col[e];
    }
    return;
  }
  id -= PB_SCAT;
  // ---- Wc = W1b @ gW ----
  gemm_body<128, 128, EPI_BF16>(smem, id & 1, id >> 1, 0,
                                W1bf + 256, 0, 512, gWT, 0, 256, 256,
                                Wc, 0, 256, nullptr, nullptr);
}

// ================= phase C: gather(2048, FIRST) | spec1(128, trailing) =================
// Gather blocks fill all CUs first (8/CU, co-phasing intact); spec1 runs in the retire tail.
// gf is a SEPARATE buffer (spec1 reads xmT concurrently with gather writing gf).
constexpr int PC_TOTAL = NBIN_ + 128;

__global__ __launch_bounds__(256) void k_phaseC(
    const u16* __restrict__ xhf, const int* __restrict__ gcnt,
    const u64* __restrict__ epB, u16* __restrict__ gf,
    const u16* __restrict__ EbfT, const u16* __restrict__ xmT, u16* __restrict__ S,
    const float* __restrict__ tpar, const float* __restrict__ evptr) {
  __shared__ __align__(16) char smem[12544];
  int id = blockIdx.x, tid = threadIdx.x;

  if (id >= NBIN_) {                        // ---- trailing spec1: S[g,k,c] (decayed) ----
    int sid = id - NBIN_;
    int zz = sid >> 2, rem = sid & 3;
    gemm_body<64, 128, EPI_DECAY>(smem, rem & 1, rem >> 1, zz,
                                  EbfT, (long)K_ * NG_, NG_, xmT, (long)C_ * NG_, NG_, NG_,
                                  S, (long)K_ * C_, C_, tpar, evptr);
    return;
  }
  int b = id;                               // ---- gather (gatherF structure, 143us known-good) ----
  unsigned* eL = (unsigned*)smem;           // [1280] 5KB
  int* chist = (int*)(smem + 5120);         // [256]
  int* roff  = chist + 256;                 // [257]
  int* sc    = roff + 257;                  // [256]
  int wave = tid >> 6, lane = tid & 63;
  int n = gcnt[b]; if (n > CAPB_) n = CAPB_;
  chist[tid] = 0;
  __syncthreads();
  const u64* ebase = epB + (size_t)b * CAPB_;
  unsigned pkr[5]; int cellr[5]; int rkr[5];
  #pragma unroll
  for (int q = 0; q < 5; ++q) {
    int i = tid + q * 256;
    bool ok = i < n;
    u64 pk = ok ? ebase[i] : 0;
    int cell = (int)((pk & 0xFFFFu) >> 13) * 32 + ((int)(pk >> 32) & 31);
    pkr[q] = (unsigned)pk; cellr[q] = cell; rkr[q] = 0;
    if (ok) rkr[q] = atomicAdd(&chist[cell], 1);
  }
  __syncthreads();
  int s = chist[tid];
  sc[tid] = s;
  __syncthreads();
  for (int o = 1; o < 256; o <<= 1) {
    int v = (tid >= o) ? sc[tid - o] : 0;
    __syncthreads();
    sc[tid] += v;
    __syncthreads();
  }
  roff[tid] = sc[tid] - s;
  if (tid == 255) roff[256] = sc[255];
  __syncthreads();
  #pragma unroll
  for (int q = 0; q < 5; ++q) {
    int i = tid + q * 256;
    if (i < n) eL[roff[cellr[q]] + rkr[q]] = pkr[q];
  }
  __syncthreads();

  const u16* xb = xhf + lane * 4;
  f32x4 acc[8];
  #pragma unroll
  for (int k = 0; k < 8; ++k) acc[k] = {0.f, 0.f, 0.f, 0.f};
  for (int t = 0; t < 8; ++t) {
    #pragma unroll
    for (int k = 0; k < 8; ++k) {
      int cell = t * 32 + wave * 8 + k;
      int j = roff[cell], en = roff[cell + 1];
      while (j < en) {
        unsigned u[4]; h16x4 xv[4];
        #pragma unroll
        for (int q = 0; q < 4; ++q) u[q] = (j + q < en) ? eL[j + q] : 0u;  // dummy: col 0, val +0
        #pragma unroll
        for (int q = 0; q < 4; ++q) xv[q] = *(const h16x4*)(xb + (size_t)(u[q] & 0xFFFFu) * C_);
        #pragma unroll
        for (int q = 0; q < 4; ++q) {
          u16 hb = (u16)(u[q] >> 16);
          _Float16 hv; __builtin_memcpy(&hv, &hb, 2);
          float v = (float)hv;
          acc[k][0] += (float)xv[q][0] * v;    // v_fma_mix_f32
          acc[k][1] += (float)xv[q][1] * v;
          acc[k][2] += (float)xv[q][2] * v;
          acc[k][3] += (float)xv[q][3] * v;
        }
        j += 4;
      }
    }
    __syncthreads();   // tile-phase alignment (L2 locality window)
  }
  int r0 = b * 32 + wave * 8;
  #pragma unroll
  for (int k = 0; k < 8; ++k) {
    ushort4 o = {f2bf(acc[k][0]), f2bf(acc[k][1]), f2bf(acc[k][2]), f2bf(acc[k][3])};
    *(ushort4*)&gf[(size_t)(r0 + k) * C_ + lane * 4] = o;
  }
}

// ================= fused MLP: h in swizzled LDS; y = x + h@W2^T + b2; LN -> out =================
__global__ __launch_bounds__(256) void k_mlp(
    const u16* __restrict__ Eb, const u16* __restrict__ Tt,
    const u16* __restrict__ gf, const u16* __restrict__ Wc,
    const float* __restrict__ bc,
    const u16* __restrict__ W2bf, const float* __restrict__ b2,
    const float* __restrict__ x, const float* __restrict__ lng, const float* __restrict__ lnb,
    float* __restrict__ out) {
  __shared__ __align__(16) u16 Asm[64 * 32];
  __shared__ __align__(16) u16 Bsm[256 * 32];
  __shared__ __align__(16) u16 hs[64 * 256];
  __shared__ float ps1[64][4], ps2[64][4];
  int i0 = blockIdx.x * 64;
  int g = i0 >> 11;
  int tid = threadIdx.x, wave = tid >> 6, lane = tid & 63;
  int wn = wave;
  int srow = wave * 16 + (lane >> 2), scol = (lane & 3) * 8;
  u16* lA = Asm + wave * 512;
  u16* lB = Bsm + wave * 512;
  int arow = lane & 15;
  int brow = wn * 64 + (lane & 15);
  int kof = (lane >> 4) * 8;

  f32x4 acc[4][4];
  #pragma unroll
  for (int m = 0; m < 4; ++m)
    #pragma unroll
    for (int n = 0; n < 4; ++n) acc[m][n] = {0.f, 0.f, 0.f, 0.f};

  {
    const u16* aA = Eb + (size_t)(i0 + srow) * K_ + scol;
    const u16* aB = Tt + (size_t)g * C_ * K_ + (size_t)srow * K_ + scol;
    for (int k0 = 0; k0 < 128; k0 += 32) {
      gload_lds16(aA + k0, lA);
      #pragma unroll
      for (int j = 0; j < 4; ++j) gload_lds16(aB + (size_t)j * 64 * K_ + k0, lB + j * 2048);
      __syncthreads();
      short8 af[4], bfr[4];
      #pragma unroll
      for (int m = 0; m < 4; ++m) af[m] = *(const short8*)(Asm + (arow + m * 16) * 32 + kof);
      #pragma unroll
      for (int n = 0; n < 4; ++n) bfr[n] = *(const short8*)(Bsm + (brow + n * 16) * 32 + kof);
      #pragma unroll
      for (int m = 0; m < 4; ++m)
        #pragma unroll
        for (int n = 0; n < 4; ++n)
          acc[m][n] = __builtin_amdgcn_mfma_f32_16x16x32_bf16(af[m], bfr[n], acc[m][n], 0, 0, 0);
      __syncthreads();
    }
  }
  {
    const u16* aA = gf + (size_t)(i0 + srow) * C_ + scol;
    const u16* aB = Wc + (size_t)srow * C_ + scol;
    for (int k0 = 0; k0 < 256; k0 += 32) {
      gload_lds16(aA + k0, lA);
      #pragma unroll
      for (int j = 0; j < 4; ++j) gload_lds16(aB + (size_t)j * 64 * C_ + k0, lB + j * 2048);
      __syncthreads();
      short8 af[4], bfr[4];
      #pragma unroll
      for (int m = 0; m < 4; ++m) af[m] = *(const short8*)(Asm + (arow + m * 16) * 32 + kof);
      #pragma unroll
      for (int n = 0; n < 4; ++n) bfr[n] = *(const short8*)(Bsm + (brow + n * 16) * 32 + kof);
      #pragma unroll
      for (int m = 0; m < 4; ++m)
        #pragma unroll
        for (int n = 0; n < 4; ++n)
          acc[m][n] = __builtin_amdgcn_mfma_f32_16x16x32_bf16(af[m], bfr[n], acc[m][n], 0, 0, 0);
      __syncthreads();
    }
  }
  #pragma unroll
  for (int n = 0; n < 4; ++n) {
    int cc = wn * 64 + n * 16 + (lane & 15);
    float bv = bc[cc];
    #pragma unroll
    for (int m = 0; m < 4; ++m) {
      #pragma unroll
      for (int r = 0; r < 4; ++r) {
        int rb = m * 16 + ((lane >> 4) << 2) + r;
        hs[(rb * 256 + cc) ^ ((rb & 7) << 3)] = f2bf(fmaxf(acc[m][n][r] + bv, 0.f));
      }
    }
  }
  __syncthreads();

  #pragma unroll
  for (int m = 0; m < 4; ++m)
    #pragma unroll
    for (int n = 0; n < 4; ++n) acc[m][n] = {0.f, 0.f, 0.f, 0.f};
  {
    const u16* aB = W2bf + (size_t)srow * C_ + scol;
    for (int k0 = 0; k0 < 256; k0 += 32) {
      #pragma unroll
      for (int j = 0; j < 4; ++j) gload_lds16(aB + (size_t)j * 64 * C_ + k0, lB + j * 2048);
      __syncthreads();
      short8 af[4], bfr[4];
      #pragma unroll
      for (int m = 0; m < 4; ++m) {
        int ar = arow + m * 16;
        af[m] = *(const short8*)(hs + ((ar * 256 + k0 + kof) ^ ((ar & 7) << 3)));
      }
      #pragma unroll
      for (int n = 0; n < 4; ++n) bfr[n] = *(const short8*)(Bsm + (brow + n * 16) * 32 + kof);
      #pragma unroll
      for (int m = 0; m < 4; ++m)
        #pragma unroll
        for (int n = 0; n < 4; ++n)
          acc[m][n] = __builtin_amdgcn_mfma_f32_16x16x32_bf16(af[m], bfr[n], acc[m][n], 0, 0, 0);
      __syncthreads();
    }
  }
  float bb[4], lg[4], lb[4];
  #pragma unroll
  for (int n = 0; n < 4; ++n) {
    int cc = wn * 64 + n * 16 + (lane & 15);
    bb[n] = b2[cc]; lg[n] = lng[cc]; lb[n] = lnb[cc];
  }
  #pragma unroll
  for (int m = 0; m < 4; ++m) {
    #pragma unroll
    for (int r = 0; r < 4; ++r) {
      int rl = m * 16 + ((lane >> 4) << 2) + r;
      #pragma unroll
      for (int n = 0; n < 4; ++n) {
        int cc = wn * 64 + n * 16 + (lane & 15);
        acc[m][n][r] += bb[n] + x[(size_t)(i0 + rl) * C_ + cc];
      }
    }
  }
  #pragma unroll
  for (int m = 0; m < 4; ++m) {
    #pragma unroll
    for (int r = 0; r < 4; ++r) {
      float t1 = acc[m][0][r] + acc[m][1][r] + acc[m][2][r] + acc[m][3][r];
      float t2 = acc[m][0][r] * acc[m][0][r] + acc[m][1][r] * acc[m][1][r] +
                 acc[m][2][r] * acc[m][2][r] + acc[m][3][r] * acc[m][3][r];
      #pragma unroll
      for (int msk = 1; msk < 16; msk <<= 1) {
        t1 += __shfl_xor(t1, msk);
        t2 += __shfl_xor(t2, msk);
      }
      if ((lane & 15) == 0) {
        int rl = m * 16 + ((lane >> 4) << 2) + r;
        ps1[rl][wn] = t1; ps2[rl][wn] = t2;
      }
    }
  }
  __syncthreads();
  #pragma unroll
  for (int m = 0; m < 4; ++m) {
    #pragma unroll
    for (int r = 0; r < 4; ++r) {
      int rl = m * 16 + ((lane >> 4) << 2) + r;
      float tot1 = ps1[rl][0] + ps1[rl][1] + ps1[rl][2] + ps1[rl][3];
      float tot2 = ps2[rl][0] + ps2[rl][1] + ps2[rl][2] + ps2[rl][3];
      float mu = tot1 * (1.f / 256.f);
      float var = fmaxf(tot2 * (1.f / 256.f) - mu * mu, 0.f);
      float rs = rsqrtf(var + 1e-5f);
      #pragma unroll
      for (int n = 0; n < 4; ++n) {
        int cc = wn * 64 + n * 16 + (lane & 15);
        out[(size_t)(i0 + rl) * C_ + cc] = (acc[m][n][r] - mu) * rs * lg[n] + lb[n];
      }
    }
  }
}

extern "C" void kernel_launch(void* const* d_in, const int* in_sizes, int n_in,
                              void* d_out, int out_size, void* d_ws, size_t ws_size,
                              hipStream_t stream) {
  const float* x        = (const float*)d_in[0];
  const float* ev       = (const float*)d_in[1];
  const float* evecs    = (const float*)d_in[2];
  const float* mass     = (const float*)d_in[3];
  const int*   row      = (const int*)d_in[4];
  const int*   col      = (const int*)d_in[5];
  const float* vals     = (const float*)d_in[6];
  const float* t_params = (const float*)d_in[7];
  const float* gW       = (const float*)d_in[8];
  const float* gb       = (const float*)d_in[9];
  const float* W1       = (const float*)d_in[10];
  const float* b1       = (const float*)d_in[11];
  const float* W2       = (const float*)d_in[12];
  const float* b2       = (const float*)d_in[13];
  const float* lng      = (const float*)d_in[14];
  const float* lnb      = (const float*)d_in[15];
  float* out = (float*)d_out;

  char* p = (char*)d_ws;
  u16* xhf  = (u16*)p; p += (size_t)N_ * C_ * 2;          // 32MB (f16 x-table for gather)
  u16* xmT  = (u16*)p; p += (size_t)G_ * C_ * NG_ * 2;    // 32MB (live through phaseC: spec1 reads it)
  u16* EbfT = (u16*)p; p += (size_t)G_ * K_ * NG_ * 2;    // 16MB
  u16* Ebf  = (u16*)p; p += (size_t)N_ * K_ * 2;          // 16MB
  u16* S    = (u16*)p; p += (size_t)G_ * K_ * C_ * 2;     // 2MB
  u16* Tt   = (u16*)p; p += (size_t)G_ * C_ * K_ * 2;     // 2MB
  u16* gf   = (u16*)p; p += (size_t)N_ * C_ * 2;          // 32MB (own buffer: spec1 || gather)
  u16* W1bf = (u16*)p; p += (size_t)C_ * 512 * 2;
  u16* W2bf = (u16*)p; p += (size_t)C_ * C_ * 2;
  u16* gWT  = (u16*)p; p += (size_t)C_ * C_ * 2;
  u16* Wc   = (u16*)p; p += (size_t)C_ * C_ * 2;
  float* bc = (float*)p; p += (size_t)C_ * 4;
  int* gcnt = (int*)p; p += (size_t)NBIN_ * 4;            // 8KB
  int* bh   = (int*)p; p += (size_t)NBIN_ * NCHK_ * 4;    // 2MB
  int* baseL= (int*)p; p += (size_t)NCHK_ * NBIN_ * 4;    // 2MB
  u64* epB  = (u64*)p; p += (size_t)NBIN_ * CAPB_ * 8;    // 21MB

  // phase A: LDS hist + all conversions + bc
  k_phaseA<<<PA_TOTAL, 256, 0, stream>>>(row, bh, x, mass, xhf, xmT,
                                         evecs, Ebf, EbfT, W1, W1bf, W2, W2bf,
                                         gW, gWT, gb, b1, bc);
  // per-bin chunk scan
  k_scanOS<<<NBIN_, 256, 0, stream>>>(bh, baseL, gcnt);
  // phase B: scatter + Wc
  k_phaseB<<<PB_TOTAL, 256, 0, stream>>>(row, col, vals, baseL, epB, W1bf, gWT, Wc);
  // phase C: gather first (fills machine), spec1 trails into the retire tail
  k_phaseC<<<PC_TOTAL, 256, 0, stream>>>(xhf, gcnt, epB, gf, EbfT, xmT, S, t_params, ev);
  // Tt[g][c][k] = (S' @ W1a^T)^T
  k_gemm<128, 128, EPI_TRANS><<<dim3(1, 2, G_), 256, 0, stream>>>(
      S, (long)K_ * C_, C_, W1bf, 0, 512, 256,
      Tt, (long)C_ * K_, K_, nullptr, nullptr);

  // fused MLP + residual + LN
  k_mlp<<<N_ / 64, 256, 0, stream>>>(Ebf, Tt, gf, Wc, bc, W2bf, b2, x, lng, lnb, out);
}